// Round 9
// baseline (50.892 us; speedup 1.0000x reference)
//
#include <hip/hip_runtime.h>

#define D4    80      // float4 per x row (D=320)
#define DIM1  10
#define DIM2  5
#define BLK   256     // 4 waves
#define RPI   16      // rows per block-iter (4 waves x 4 rows)
#define ITERS 17
#define CROWS (RPI * ITERS)   // 272 t-rows computed (incl. +-2 halo)
#define OROWS (CROWS - 4)     // 268 output rows per block; grid 747 <= 768 capacity
#define NREG  4               // W1 rows (d) held in registers per lane
#define NLDS  (DIM1 - NREG)   // 6 W1 rows read from LDS

typedef float __attribute__((ext_vector_type(4))) f32x4;
typedef float __attribute__((ext_vector_type(2))) f32x2;

// packed 2-wide fp32 FMA: acc = a*b + acc (one VOP3P inst, halves FMA issue count)
#define PKFMA(acc, a, b) \
    asm("v_pk_fma_f32 %0, %1, %2, %0" : "+v"(acc) : "v"(a), "v"(b))

// 16-lane sum via DPP row_ror (pure VALU, no lgkmcnt). Validated R3..R8.
__device__ __forceinline__ float row16_sum(float v) {
    int p;
    p = __builtin_amdgcn_update_dpp(0, __float_as_int(v), 0x128, 0xF, 0xF, true); // row_ror:8
    v += __int_as_float(p);
    p = __builtin_amdgcn_update_dpp(0, __float_as_int(v), 0x124, 0xF, 0xF, true); // row_ror:4
    v += __int_as_float(p);
    p = __builtin_amdgcn_update_dpp(0, __float_as_int(v), 0x122, 0xF, 0xF, true); // row_ror:2
    v += __int_as_float(p);
    p = __builtin_amdgcn_update_dpp(0, __float_as_int(v), 0x121, 0xF, 0xF, true); // row_ror:1
    v += __int_as_float(p);
    return v;
}

// Per wave: 4 rows x 16 lanes. s = lane&15 (K-slot: 5 f4 at stride 16),
// g = lane>>4 (row in quad). All 64 lanes load DISTINCT x float4s.
// W1: d<4 in regs, d>=4 from LDS (broadcast/2-way alias = free).
// Inner dots use v_pk_fma_f32 (2 MACs/inst) -> ~100 cyc/row VALU < 125 cyc/row HBM.
__global__ __launch_bounds__(BLK, 3)
void fused_fcl_win(const f32x4* __restrict__ x4,
                   const f32x4* __restrict__ w1g,    // W1 as f4[10*80]
                   const float* __restrict__ w2,     // [5][10]
                   const float* __restrict__ b2,     // [5]
                   float*       __restrict__ out,
                   int N)
{
    __shared__ f32x4 w1s[NLDS * D4];        // 480 f4 = 7.68 KB
    __shared__ float t_lds[CROWS * DIM2];   // 1360 floats = 5.44 KB

    const int tid  = threadIdx.x;
    const int lane = tid & 63;
    const int wave = tid >> 6;
    const int s    = lane & 15;
    const int g    = lane >> 4;
    const int slot = wave * 4 + g;          // row slot within iter (0..15)

    // stage W1[d=NREG..9] to LDS (one-time per block)
    for (int f = tid; f < NLDS * D4; f += BLK)
        w1s[f] = w1g[NREG * D4 + f];

    // register-resident W1[d=0..NREG-1] slice for this lane's K-slot, as f32x2 pairs
    f32x2 w1r[NREG][10];
    #pragma unroll
    for (int dd = 0; dd < NREG; ++dd)
        #pragma unroll
        for (int i = 0; i < 5; ++i) {
            f32x4 w = w1g[dd * D4 + s + 16 * i];
            w1r[dd][2 * i]     = __builtin_shufflevector(w, w, 0, 1);
            w1r[dd][2 * i + 1] = __builtin_shufflevector(w, w, 2, 3);
        }

    // lane s<5 owns output channel s: full W2 row + bias
    const int j = (s < DIM2) ? s : 0;
    float w2r[DIM1];
    #pragma unroll
    for (int d = 0; d < DIM1; ++d) w2r[d] = w2[j * DIM1 + d];
    const float b2r = b2[j];

    __syncthreads();

    const int base = (int)blockIdx.x * OROWS;
    // interior blocks need no row clamp: rows [base-2, base+CROWS-3] all in [0,N)
    const bool safe = (base >= 2) && (base + CROWS - 2 <= N);
    const f32x4* xpb = x4 + (size_t)(base - 2 + slot) * D4 + s;  // only deref'd when safe

    auto loadrow = [&](int it, f32x4* xv) {
        if (safe) {
            const f32x4* p = xpb + (size_t)it * (RPI * D4);   // pointer-bump fast path
            #pragma unroll
            for (int i = 0; i < 5; ++i) xv[i] = p[i * 16];
        } else {
            int r  = base - 2 + it * RPI + slot;
            int rc = min(max(r, 0), N - 1);                   // clamp keeps load legal
            const f32x4* xp = x4 + (size_t)rc * D4 + s;
            #pragma unroll
            for (int i = 0; i < 5; ++i) xv[i] = xp[i * 16];
        }
    };

    f32x4 xv[5];
    loadrow(0, xv);

    int wofs = 0;   // opaque LDS f4-offset: blocks LICM from hoisting W1 reads
    for (int it = 0; it < ITERS; ++it) {
        f32x4 xn[5];
        if (it + 1 < ITERS) loadrow(it + 1, xn);   // 1-deep prefetch

        asm volatile("" : "+v"(wofs));

        // x pairs (register aliases of the loaded quads)
        f32x2 x2[10];
        #pragma unroll
        for (int i = 0; i < 5; ++i) {
            x2[2 * i]     = __builtin_shufflevector(xv[i], xv[i], 0, 1);
            x2[2 * i + 1] = __builtin_shufflevector(xv[i], xv[i], 2, 3);
        }

        float partial = b2r;
        #pragma unroll
        for (int dd = 0; dd < NREG; ++dd) {
            f32x2 acc2 = {0.f, 0.f};
            #pragma unroll
            for (int q = 0; q < 10; ++q) PKFMA(acc2, w1r[dd][q], x2[q]);
            float acc = acc2.x + acc2.y;
            acc = row16_sum(acc);
            partial += fmaxf(acc, 0.f) * w2r[dd];
        }
        #pragma unroll
        for (int dd = 0; dd < NLDS; ++dd) {
            f32x2 acc2 = {0.f, 0.f};
            #pragma unroll
            for (int i = 0; i < 5; ++i) {
                f32x4 w = w1s[wofs + dd * D4 + s + 16 * i];   // b128 read, broadcast: free
                f32x2 wlo = __builtin_shufflevector(w, w, 0, 1);
                f32x2 whi = __builtin_shufflevector(w, w, 2, 3);
                PKFMA(acc2, wlo, x2[2 * i]);
                PKFMA(acc2, whi, x2[2 * i + 1]);
            }
            float acc = acc2.x + acc2.y;
            acc = row16_sum(acc);
            partial += fmaxf(acc, 0.f) * w2r[NREG + dd];
        }
        float t5 = fmaxf(partial, 0.f);

        const int r = base - 2 + it * RPI + slot;
        if (r < 0 || r >= N) t5 = 0.f;       // zero-pad window semantics
        if (s < DIM2)
            t_lds[(it * RPI + slot) * DIM2 + s] = t5;

        #pragma unroll
        for (int i = 0; i < 5; ++i) xv[i] = xn[i];
    }
    __syncthreads();

    // window expansion: out[n, a*5+jj] = t[n+a-2, jj]; flat e=nr*25+c -> lds idx e-20*nr
    const int lim = min(OROWS, N - base);
    const int nf  = lim * 25;
    float*    ob  = out + (size_t)base * 25;   // 16B-aligned (base*25 % 4 == 0)
    const int nf4 = nf >> 2;
    for (int f = tid; f < nf4; f += BLK) {
        int e   = f * 4;
        int nr  = e / 25;
        int c   = e - nr * 25;
        int idx = nr * 5 + c;
        float v[4];
        #pragma unroll
        for (int u = 0; u < 4; ++u) {
            v[u] = t_lds[idx];
            ++c; ++idx;
            if (c == 25) { c = 0; idx -= 20; }
        }
        f32x4 vv = { v[0], v[1], v[2], v[3] };
        __builtin_nontemporal_store(vv, (f32x4*)(ob + e));
    }
    for (int e = (nf & ~3) + tid; e < nf; e += BLK) {   // tail (last block only)
        int nr = e / 25;
        ob[e] = t_lds[e - 20 * nr];
    }
}

extern "C" void kernel_launch(void* const* d_in, const int* in_sizes, int n_in,
                              void* d_out, int out_size, void* d_ws, size_t ws_size,
                              hipStream_t stream)
{
    const f32x4* x4 = (const f32x4*)d_in[0];
    const f32x4* w1 = (const f32x4*)d_in[1];
    const float* w2 = (const float*)d_in[2];
    const float* b2 = (const float*)d_in[3];

    const int N = in_sizes[0] / 320;   // 200000
    float* out = (float*)d_out;

    const int grid = (N + OROWS - 1) / OROWS;   // 747 blocks <= 768 capacity
    fused_fcl_win<<<grid, BLK, 0, stream>>>(x4, w1, w2, b2, out, N);
}

// Round 10
// 50.224 us; speedup vs baseline: 1.0133x; 1.0133x over previous
//
#include <hip/hip_runtime.h>

#define D4    80      // float4 per x row (D=320)
#define DIM1  10
#define DIM2  5
#define BLK   256     // 4 waves
#define RPI   16      // rows per block-iter (4 waves x 4 rows)
#define ITERS 17
#define CROWS (RPI * ITERS)   // 272 t-rows computed (incl. +-2 halo)
#define OROWS (CROWS - 4)     // 268 output rows per block; grid 747 <= 768 capacity
#define NREG  4               // W1 rows (d) held in registers per lane
#define NLDS  (DIM1 - NREG)   // 6 W1 rows read from LDS

typedef float __attribute__((ext_vector_type(4))) f32x4;

// 16-lane sum via DPP row_ror (pure VALU, no lgkmcnt). Validated R3..R9.
__device__ __forceinline__ float row16_sum(float v) {
    int p;
    p = __builtin_amdgcn_update_dpp(0, __float_as_int(v), 0x128, 0xF, 0xF, true); // row_ror:8
    v += __int_as_float(p);
    p = __builtin_amdgcn_update_dpp(0, __float_as_int(v), 0x124, 0xF, 0xF, true); // row_ror:4
    v += __int_as_float(p);
    p = __builtin_amdgcn_update_dpp(0, __float_as_int(v), 0x122, 0xF, 0xF, true); // row_ror:2
    v += __int_as_float(p);
    p = __builtin_amdgcn_update_dpp(0, __float_as_int(v), 0x121, 0xF, 0xF, true); // row_ror:1
    v += __int_as_float(p);
    return v;
}

__device__ __forceinline__ float dot4(f32x4 a, f32x4 b) {
    return a.x * b.x + a.y * b.y + a.z * b.z + a.w * b.w;
}

// Per wave: 4 rows x 16 lanes. s = lane&15 (K-slot: 5 f4 at stride 16),
// g = lane>>4 (row in quad). All 64 lanes load DISTINCT x float4s.
// W1: d<4 in regs (80 VGPR), d>=4 from LDS (broadcast/2-way alias = free).
// Grid = 747 blocks <= 768 co-resident capacity -> single uniform round.
// Memory-bound at ~5.6 TB/s effective (89% of copy ceiling); compute-side
// levers (pk_fma, layout, occupancy) all measured null (R6, R9).
__global__ __launch_bounds__(BLK, 3)
void fused_fcl_win(const f32x4* __restrict__ x4,
                   const f32x4* __restrict__ w1g,    // W1 as f4[10*80]
                   const float* __restrict__ w2,     // [5][10]
                   const float* __restrict__ b2,     // [5]
                   float*       __restrict__ out,
                   int N)
{
    __shared__ f32x4 w1s[NLDS * D4];        // 480 f4 = 7.68 KB
    __shared__ float t_lds[CROWS * DIM2];   // 1360 floats = 5.44 KB

    const int tid  = threadIdx.x;
    const int lane = tid & 63;
    const int wave = tid >> 6;
    const int s    = lane & 15;
    const int g    = lane >> 4;
    const int slot = wave * 4 + g;          // row slot within iter (0..15)

    // stage W1[d=NREG..9] to LDS (one-time per block, amortized over 17 iters)
    for (int f = tid; f < NLDS * D4; f += BLK)
        w1s[f] = w1g[NREG * D4 + f];

    // register-resident W1[d=0..NREG-1] slice for this lane's K-slot
    f32x4 w1r[NREG][5];
    #pragma unroll
    for (int dd = 0; dd < NREG; ++dd)
        #pragma unroll
        for (int i = 0; i < 5; ++i)
            w1r[dd][i] = w1g[dd * D4 + s + 16 * i];

    // lane s<5 owns output channel s: full W2 row + bias
    const int j = (s < DIM2) ? s : 0;
    float w2r[DIM1];
    #pragma unroll
    for (int d = 0; d < DIM1; ++d) w2r[d] = w2[j * DIM1 + d];
    const float b2r = b2[j];

    __syncthreads();

    const int base = (int)blockIdx.x * OROWS;
    // interior blocks need no row clamp: rows [base-2, base+CROWS-3] all in [0,N)
    const bool safe = (base >= 2) && (base + CROWS - 2 <= N);
    const f32x4* xpb = x4 + (size_t)(base - 2 + slot) * D4 + s;  // only deref'd when safe

    auto loadrow = [&](int it, f32x4* xv) {
        if (safe) {
            const f32x4* p = xpb + (size_t)it * (RPI * D4);   // pointer-bump fast path
            #pragma unroll
            for (int i = 0; i < 5; ++i) xv[i] = p[i * 16];
        } else {
            int r  = base - 2 + it * RPI + slot;
            int rc = min(max(r, 0), N - 1);                   // clamp keeps load legal
            const f32x4* xp = x4 + (size_t)rc * D4 + s;
            #pragma unroll
            for (int i = 0; i < 5; ++i) xv[i] = xp[i * 16];
        }
    };

    f32x4 xv[5];
    loadrow(0, xv);

    int wofs = 0;   // opaque LDS f4-offset: blocks LICM from hoisting W1 reads
    for (int it = 0; it < ITERS; ++it) {
        f32x4 xn[5];
        if (it + 1 < ITERS) loadrow(it + 1, xn);   // 1-deep prefetch

        asm volatile("" : "+v"(wofs));

        float partial = b2r;
        #pragma unroll
        for (int dd = 0; dd < NREG; ++dd) {
            float acc = 0.f;
            #pragma unroll
            for (int i = 0; i < 5; ++i) acc += dot4(w1r[dd][i], xv[i]);
            acc = row16_sum(acc);
            partial += fmaxf(acc, 0.f) * w2r[dd];
        }
        #pragma unroll
        for (int dd = 0; dd < NLDS; ++dd) {
            float acc = 0.f;
            #pragma unroll
            for (int i = 0; i < 5; ++i) {
                f32x4 w = w1s[wofs + dd * D4 + s + 16 * i];   // broadcast: free
                acc += dot4(w, xv[i]);
            }
            acc = row16_sum(acc);
            partial += fmaxf(acc, 0.f) * w2r[NREG + dd];
        }
        float t5 = fmaxf(partial, 0.f);

        const int r = base - 2 + it * RPI + slot;
        if (r < 0 || r >= N) t5 = 0.f;       // zero-pad window semantics
        if (s < DIM2)
            t_lds[(it * RPI + slot) * DIM2 + s] = t5;

        #pragma unroll
        for (int i = 0; i < 5; ++i) xv[i] = xn[i];
    }
    __syncthreads();

    // window expansion: out[n, a*5+jj] = t[n+a-2, jj]; flat e=nr*25+c -> lds idx e-20*nr
    const int lim = min(OROWS, N - base);
    const int nf  = lim * 25;
    float*    ob  = out + (size_t)base * 25;   // 16B-aligned (base*25 % 4 == 0)
    const int nf4 = nf >> 2;
    for (int f = tid; f < nf4; f += BLK) {
        int e   = f * 4;
        int nr  = e / 25;
        int c   = e - nr * 25;
        int idx = nr * 5 + c;
        float v[4];
        #pragma unroll
        for (int u = 0; u < 4; ++u) {
            v[u] = t_lds[idx];
            ++c; ++idx;
            if (c == 25) { c = 0; idx -= 20; }
        }
        f32x4 vv = { v[0], v[1], v[2], v[3] };
        __builtin_nontemporal_store(vv, (f32x4*)(ob + e));
    }
    for (int e = (nf & ~3) + tid; e < nf; e += BLK) {   // tail (last block only)
        int nr = e / 25;
        ob[e] = t_lds[e - 20 * nr];
    }
}

extern "C" void kernel_launch(void* const* d_in, const int* in_sizes, int n_in,
                              void* d_out, int out_size, void* d_ws, size_t ws_size,
                              hipStream_t stream)
{
    const f32x4* x4 = (const f32x4*)d_in[0];
    const f32x4* w1 = (const f32x4*)d_in[1];
    const float* w2 = (const float*)d_in[2];
    const float* b2 = (const float*)d_in[3];

    const int N = in_sizes[0] / 320;   // 200000
    float* out = (float*)d_out;

    const int grid = (N + OROWS - 1) / OROWS;   // 747 blocks <= 768 capacity
    fused_fcl_win<<<grid, BLK, 0, stream>>>(x4, w1, w2, b2, out, N);
}